// Round 1
// baseline (753.663 us; speedup 1.0000x reference)
//
#include <hip/hip_runtime.h>

#pragma clang fp contract(off)

// Problem constants (from reference)
#define NB 16      // N
#define NRR 300    // NR == NR_SO
#define KTOP 10    // K

// Output layout (floats), concatenated in return order:
// so_pro_out (16,320,512) | boxes_so_out (16,320,8) | so_cls_out (16,320,300)
// rel_out (16,320,256)    | so_roi_out (16,320,12544) | vis_out (16,300)
#define OFF_PRO 0
#define OFF_BOX 2621440
#define OFF_CLS 2662400
#define OFF_REL 4198400
#define OFF_ROI 5509120
#define OFF_VIS 69734400

__device__ __forceinline__ float sigm(float x){ return 1.0f/(1.0f + expf(-x)); }

// ---------------------------------------------------------------------------
// Kernel A: one wave per (n,pair). Top-3 subject/object probs+classes
// (tie -> lowest index, matching jax.lax.top_k) and rel_max.
// ---------------------------------------------------------------------------
__global__ __launch_bounds__(256) void k_pair(
    const float* __restrict__ so_cls, const float* __restrict__ rel_logits,
    float* __restrict__ s_score, int* __restrict__ s_class,
    float* __restrict__ o_score, int* __restrict__ o_class,
    float* __restrict__ relmax)
{
  int wid  = (blockIdx.x * 256 + threadIdx.x) >> 6;
  int lane = threadIdx.x & 63;
  if (wid >= NB * NRR) return;
  const float* row = so_cls + (size_t)wid * 300;

  for (int half = 0; half < 2; ++half) {
    const float* r = row + half * 150;
    float v[3]; int ci[3];
    #pragma unroll
    for (int j = 0; j < 3; ++j) {
      int c = lane + j * 64;
      ci[j] = c;
      v[j]  = (c < 150) ? r[c] : -1e38f;
    }
    float* ss = half ? o_score : s_score;
    int*   sc = half ? o_class : s_class;
    for (int rd = 0; rd < 3; ++rd) {
      // lane-local argmax (ascending c, strict > keeps lowest index on tie)
      float bv = v[0]; int bi = ci[0];
      if (v[1] > bv) { bv = v[1]; bi = ci[1]; }
      if (v[2] > bv) { bv = v[2]; bi = ci[2]; }
      // wave argmax, tie -> min index
      #pragma unroll
      for (int off = 32; off >= 1; off >>= 1) {
        float ov = __shfl_xor(bv, off, 64);
        int   oi = __shfl_xor(bi, off, 64);
        if (ov > bv || (ov == bv && oi < bi)) { bv = ov; bi = oi; }
      }
      if (lane == 0) { ss[wid*3 + rd] = sigm(bv); sc[wid*3 + rd] = bi; }
      #pragma unroll
      for (int j = 0; j < 3; ++j) if (ci[j] == bi) v[j] = -1e38f;
    }
  }
  // rel_max = max(sigmoid(rel_logits)) = sigmoid(max logit) (monotone)
  float m = (lane < 50) ? rel_logits[(size_t)wid * 50 + lane] : -1e38f;
  #pragma unroll
  for (int off = 32; off >= 1; off >>= 1) m = fmaxf(m, __shfl_xor(m, off, 64));
  if (lane == 0) relmax[wid] = sigm(m);
}

// ---------------------------------------------------------------------------
// Kernel B: one block per batch. Exact top-100 of 2700 triple scores via
// bitonic sort of (valbits, ~flatidx) keys (desc value, lowest idx on tie).
// Then ascending index sort; emit sel_class (200) and sel_boxes (200x4).
// ---------------------------------------------------------------------------
__global__ __launch_bounds__(256) void k_tri100(
    const float* __restrict__ s_score, const int* __restrict__ s_class,
    const float* __restrict__ o_score, const int* __restrict__ o_class,
    const float* __restrict__ relmax,  const float* __restrict__ pbso,
    int* __restrict__ sel_class, float* __restrict__ sel_boxes)
{
  __shared__ unsigned long long keys[4096];
  __shared__ int sidx[128];
  int n = blockIdx.x, tid = threadIdx.x;

  for (int f = tid; f < 4096; f += 256) {
    unsigned long long key = 0ull;
    if (f < 2700) {
      int k = f / 9, p = f - k * 9;
      float s = s_score[(n*NRR + k)*3 + p/3];
      float o = o_score[(n*NRR + k)*3 + (p - (p/3)*3)];
      float v = (relmax[n*NRR + k] * s) * o;   // left-assoc, matches reference
      key = ((unsigned long long)__float_as_uint(v) << 32)
          | (unsigned long long)(0xFFFFFFFFu - (unsigned)f);
    }
    keys[f] = key;
  }
  __syncthreads();
  // bitonic sort, descending
  for (int k = 2; k <= 4096; k <<= 1) {
    for (int j = k >> 1; j > 0; j >>= 1) {
      for (int i = tid; i < 4096; i += 256) {
        int l = i ^ j;
        if (l > i) {
          unsigned long long a = keys[i], b = keys[l];
          bool up = ((i & k) == 0);
          if ((a < b) == up) { keys[i] = b; keys[l] = a; }
        }
      }
      __syncthreads();
    }
  }
  if (tid < 128)
    sidx[tid] = (tid < 100) ? (int)(0xFFFFFFFFu - (unsigned)(keys[tid] & 0xFFFFFFFFull))
                            : 0x7FFFFFFF;
  __syncthreads();
  // ascending sort of the 100 selected flat indices (pad sorts last)
  for (int k = 2; k <= 128; k <<= 1) {
    for (int j = k >> 1; j > 0; j >>= 1) {
      if (tid < 64) {
        for (int i = tid; i < 128; i += 64) {
          int l = i ^ j;
          if (l > i) {
            int a = sidx[i], b = sidx[l];
            bool up = ((i & k) == 0);
            if ((a > b) == up) { sidx[i] = b; sidx[l] = a; }
          }
        }
      }
      __syncthreads();
    }
  }
  if (tid < 200) {
    int m = tid, j = m >> 1, side = m & 1;
    int f = sidx[j];
    int k2 = f / 9, p = f - k2 * 9;
    sel_class[n*200 + m] = side ? o_class[(n*NRR + k2)*3 + (p - (p/3)*3)]
                                : s_class[(n*NRR + k2)*3 + p/3];
    const float4 b = *(const float4*)(pbso + (size_t)(n*NRR + k2)*8 + side*4);
    *(float4*)(sel_boxes + (size_t)(n*200 + m)*4) = b;
  }
}

// ---------------------------------------------------------------------------
// Kernel C: one wave per (n,entity). argmax class, IoU-dedup vs 200 selected,
// entity score.
// ---------------------------------------------------------------------------
__global__ __launch_bounds__(256) void k_entity(
    const float* __restrict__ class_logits, const float* __restrict__ pred_bboxes,
    const int* __restrict__ sel_class, const float* __restrict__ sel_boxes,
    const unsigned char* __restrict__ vis, float* __restrict__ score)
{
  int wid  = (blockIdx.x * 256 + threadIdx.x) >> 6;
  int lane = threadIdx.x & 63;
  if (wid >= NB * NRR) return;
  int n = wid / NRR, i = wid - n * NRR;

  const float* r = class_logits + (size_t)(n*600 + 2*i) * 150;
  float bv = r[lane]; int bi = lane;
  for (int c = lane + 64; c < 150; c += 64) {
    float x = r[c];
    if (x > bv) { bv = x; bi = c; }
  }
  #pragma unroll
  for (int off = 32; off >= 1; off >>= 1) {
    float ov = __shfl_xor(bv, off, 64);
    int   oi = __shfl_xor(bi, off, 64);
    if (ov > bv || (ov == bv && oi < bi)) { bv = ov; bi = oi; }
  }
  float maxp = sigm(bv);

  const float* b1 = pred_bboxes + (size_t)(n*600 + 2*i) * 4;
  float x1 = b1[0], y1 = b1[1], x2 = b1[2], y2 = b1[3];
  float a1 = (y2 - y1 + 1.0f) * (x2 - x1 + 1.0f);

  bool hit = false;
  for (int m = lane; m < 200; m += 64) {
    if (sel_class[n*200 + m] == bi) {
      const float4 b2 = *(const float4*)(sel_boxes + (size_t)(n*200 + m)*4);
      float a2 = (b2.w - b2.y + 1.0f) * (b2.z - b2.x + 1.0f);
      float w = fminf(x2, b2.z) - fmaxf(x1, b2.x); if (w < 0.f) w = 0.f;
      float h = fminf(y2, b2.w) - fmaxf(y1, b2.y); if (h < 0.f) h = 0.f;
      float inter = w * h;
      float iou = inter / ((a1 + a2) - inter);
      if (iou >= 0.5f) hit = true;
    }
  }
  bool any = (__ballot(hit) != 0ull);
  if (lane == 0)
    score[wid] = maxp - (any ? 2.0f : 0.0f) - (vis[n*NRR + i] ? 2.0f : 0.0f);
}

// ---------------------------------------------------------------------------
// Kernel D: one block per batch. Top-10 entity indices (tie -> lowest idx),
// sorted ascending; writes ent_idx to ws and vis_out to d_out.
// ---------------------------------------------------------------------------
__global__ __launch_bounds__(256) void k_top10(
    const float* __restrict__ score, const unsigned char* __restrict__ vis,
    int* __restrict__ ent, float* __restrict__ vis_out)
{
  __shared__ unsigned long long keys[512];
  __shared__ int top[16];
  int n = blockIdx.x, tid = threadIdx.x;

  for (int i = tid; i < 512; i += 256) {
    unsigned long long key = 0ull;
    if (i < NRR) {
      unsigned u = __float_as_uint(score[n*NRR + i]);
      u = (u & 0x80000000u) ? ~u : (u | 0x80000000u);   // order-preserving map
      key = ((unsigned long long)u << 32)
          | (unsigned long long)(0xFFFFFFFFu - (unsigned)i);
    }
    keys[i] = key;
  }
  __syncthreads();
  for (int k = 2; k <= 512; k <<= 1) {
    for (int j = k >> 1; j > 0; j >>= 1) {
      for (int i = tid; i < 512; i += 256) {
        int l = i ^ j;
        if (l > i) {
          unsigned long long a = keys[i], b = keys[l];
          bool up = ((i & k) == 0);
          if ((a < b) == up) { keys[i] = b; keys[l] = a; }
        }
      }
      __syncthreads();
    }
  }
  if (tid == 0) {
    int tmp[10];
    for (int j = 0; j < 10; ++j)
      tmp[j] = (int)(0xFFFFFFFFu - (unsigned)(keys[j] & 0xFFFFFFFFull));
    for (int a = 1; a < 10; ++a) {            // ascending insertion sort
      int x = tmp[a], b = a - 1;
      while (b >= 0 && tmp[b] > x) { tmp[b+1] = tmp[b]; --b; }
      tmp[b+1] = x;
    }
    for (int j = 0; j < 10; ++j) { top[j] = tmp[j]; ent[n*KTOP + j] = tmp[j]; }
  }
  __syncthreads();
  for (int i = tid; i < NRR; i += 256) {
    bool m = vis[n*NRR + i] != 0;
    #pragma unroll
    for (int j = 0; j < 10; ++j) m = m || (top[j] == i);
    vis_out[n*NRR + i] = m ? 1.0f : 0.0f;
  }
}

// ---------------------------------------------------------------------------
// Copy/gather kernels: dst rows 0..299 = main_src; 300..309 = gathered rows;
// 310..319 = MODE 0: swapped halves of gathered row (gather row len == D)
//            MODE 1: second half of a 2*D-wide gather row (rel / aux split)
// D,G in units of V. 16-byte (float4) or 8-byte (float2) vectorized.
// ---------------------------------------------------------------------------
template <int D, int G, int MODE, typename V>
__global__ __launch_bounds__(256) void k_fuse(
    const V* __restrict__ msrc, const V* __restrict__ gsrc,
    V* __restrict__ dst, const int* __restrict__ ent)
{
  int t = blockIdx.x * 256 + threadIdx.x;
  constexpr int TOT = NB * 320 * D;
  if (t >= TOT) return;
  int bi = t / D, c = t - bi * D;
  int n = bi / 320, row = bi - n * 320;
  V val;
  if (row < 300) {
    val = msrc[(size_t)(n*NRR + row) * D + c];
  } else {
    int e = ent[n*KTOP + (row < 310 ? row - 300 : row - 310)];
    int cc;
    if (row < 310)            cc = c;
    else if (MODE == 0)       cc = (c >= D/2) ? (c - D/2) : (c + D/2);
    else                      cc = D + c;
    val = gsrc[(size_t)(n*NRR + e) * G + cc];
  }
  dst[t] = val;
}

// ---------------------------------------------------------------------------
extern "C" void kernel_launch(void* const* d_in, const int* in_sizes, int n_in,
                              void* d_out, int out_size, void* d_ws, size_t ws_size,
                              hipStream_t stream) {
  const float* aux_rel        = (const float*)d_in[0];
  const float* class_logits   = (const float*)d_in[1];
  const float* pred_bboxes    = (const float*)d_in[2];
  const float* pro_features   = (const float*)d_in[3];
  const float* roi_features   = (const float*)d_in[4];
  const float* so_cls         = (const float*)d_in[5];
  const float* pred_bboxes_so = (const float*)d_in[6];
  const float* so_pro         = (const float*)d_in[7];
  const float* so_roi         = (const float*)d_in[8];
  const float* rel_logits     = (const float*)d_in[9];
  const float* rel_feat       = (const float*)d_in[10];
  const unsigned char* vis    = (const unsigned char*)d_in[11];
  float* out = (float*)d_out;

  // workspace carve (floats): 333,440 bytes total
  float* ws        = (float*)d_ws;
  float* s_score   = ws;                    // 16*300*3
  float* o_score   = ws + 14400;            // 16*300*3
  int*   s_class   = (int*)(ws + 28800);    // 16*300*3
  int*   o_class   = (int*)(ws + 43200);    // 16*300*3
  float* relmax    = ws + 57600;            // 16*300
  int*   sel_class = (int*)(ws + 62400);    // 16*200
  float* sel_boxes = ws + 65600;            // 16*200*4
  float* score     = ws + 78400;            // 16*300
  int*   ent       = (int*)(ws + 83200);    // 16*10

  k_pair  <<<1200, 256, 0, stream>>>(so_cls, rel_logits, s_score, s_class,
                                     o_score, o_class, relmax);
  k_tri100<<<  16, 256, 0, stream>>>(s_score, s_class, o_score, o_class, relmax,
                                     pred_bboxes_so, sel_class, sel_boxes);
  k_entity<<<1200, 256, 0, stream>>>(class_logits, pred_bboxes, sel_class,
                                     sel_boxes, vis, score);
  k_top10 <<<  16, 256, 0, stream>>>(score, vis, ent, out + OFF_VIS);

  k_fuse<128, 128, 0, float4><<< 2560, 256, 0, stream>>>(
      (const float4*)so_pro, (const float4*)pro_features,
      (float4*)(out + OFF_PRO), ent);
  k_fuse<  2,   2, 0, float4><<<   40, 256, 0, stream>>>(
      (const float4*)pred_bboxes_so, (const float4*)pred_bboxes,
      (float4*)(out + OFF_BOX), ent);
  k_fuse<150, 150, 0, float2><<< 3000, 256, 0, stream>>>(
      (const float2*)so_cls, (const float2*)class_logits,
      (float2*)(out + OFF_CLS), ent);
  k_fuse< 64, 128, 1, float4><<< 1280, 256, 0, stream>>>(
      (const float4*)rel_feat, (const float4*)aux_rel,
      (float4*)(out + OFF_REL), ent);
  k_fuse<3136, 3136, 0, float4><<<62720, 256, 0, stream>>>(
      (const float4*)so_roi, (const float4*)roi_features,
      (float4*)(out + OFF_ROI), ent);
}